// Round 10
// baseline (53.945 us; speedup 1.0000x reference)
//
#include <hip/hip_runtime.h>

typedef unsigned long long u64;
typedef unsigned int u32;
typedef float f32x4 __attribute__((ext_vector_type(4)));

#define B_  32
#define S_  1024
#define K_  16
#define NTK 128     // threads/block (2 waves)
#define LPQ 16      // lanes per query
#define QPB 8       // queries per block (NTK/LPQ)

// key = double whose bit pattern is (d2_f32_bits << 32) | j.
// d2 >= 0 -> high word in [0, 0x7F7FFFFF] -> positive finite double,
// so IEEE fmin/fmax (v_min_f64/v_max_f64) order keys exactly as u64.
__device__ __forceinline__ double pack_key(float d2, int j) {
    return __longlong_as_double(((u64)__float_as_uint(d2) << 32) | (u32)j);
}

// ascending compare-exchange: 2 VALU instrs
__device__ __forceinline__ void ce(double& a, double& b) {
    const double lo = fmin(a, b);
    const double hi = fmax(a, b);
    a = lo; b = hi;
}

// Batcher odd-even mergesort of 8 keys, 19 CE, depth 6, ascending
__device__ __forceinline__ void sort8(double (&k)[8]) {
    ce(k[0], k[1]); ce(k[2], k[3]); ce(k[4], k[5]); ce(k[6], k[7]);
    ce(k[0], k[2]); ce(k[1], k[3]); ce(k[4], k[6]); ce(k[5], k[7]);
    ce(k[1], k[2]); ce(k[5], k[6]);
    ce(k[0], k[4]); ce(k[1], k[5]); ce(k[2], k[6]); ce(k[3], k[7]);
    ce(k[2], k[4]); ce(k[3], k[5]);
    ce(k[1], k[2]); ce(k[3], k[4]); ce(k[5], k[6]);
}

// clean a bitonic 16-sequence into ascending order (4 stages, 32 CE)
__device__ __forceinline__ void clean16(double (&k)[16]) {
#pragma unroll
    for (int str = 8; str > 0; str >>= 1) {
#pragma unroll
        for (int t = 0; t < 16; ++t) {
            const int p = t ^ str;
            if (p > t) ce(k[t], k[p]);
        }
    }
}

__device__ __forceinline__ void nt_store4(float4 v, float4* p) {
    f32x4 w;
    w.x = v.x; w.y = v.y; w.z = v.z; w.w = v.w;
    __builtin_nontemporal_store(w, (f32x4*)p);
}

__global__ __launch_bounds__(NTK, 5)
void knn_fused(const float* __restrict__ pos, const float* __restrict__ x,
               const float* __restrict__ Wm, const float* __restrict__ bv,
               float* __restrict__ out) {
    __shared__ float4 spos[S_];             // 16 KB -> 10 blocks/CU resident

    const int tid   = threadIdx.x;
    const int cloud = blockIdx.x >> 7;      // 128 blocks per cloud
    const int qbase = (blockIdx.x & 127) * QPB;
    const int base  = cloud * S_;

    for (int r = tid; r < S_; r += NTK) {
        const float* p = pos + (size_t)(base + r) * 3;
        spos[r] = make_float4(p[0], p[1], p[2], 0.0f);
    }
    __syncthreads();

    const int s  = tid & (LPQ - 1);         // slice: j = s (mod 16)
    const int qi = qbase + (tid >> 4);      // query within cloud
    const float4 pi = spos[qi];
    const float pix = pi.x, piy = pi.y, piz = pi.z;

    double key[16];
#pragma unroll
    for (int t = 0; t < 16; ++t)
        key[t] = __longlong_as_double(0x7FEFFFFFFFFFFFFFULL);  // > any real key

    const float4* sp = &spos[s];            // lane slice pointer, stride 16
    float4 buf[8];                          // software-pipelined chunk loads
#pragma unroll
    for (int u = 0; u < 8; ++u) buf[u] = sp[16 * u];

    int jlow = s;                           // local j of buf[0]
    for (int c = 0; c < 8; ++c) {           // 8 chunks x 8 candidates = 64
        double nk[8];
#pragma unroll
        for (int u = 0; u < 8; ++u) {
            // bit-exact numpy chain: no fma, (dx2+dy2)+dz2
            const float dx = __fsub_rn(pix, buf[u].x);
            const float dy = __fsub_rn(piy, buf[u].y);
            const float dz = __fsub_rn(piz, buf[u].z);
            const float d2 = __fadd_rn(
                __fadd_rn(__fmul_rn(dx, dx), __fmul_rn(dy, dy)),
                __fmul_rn(dz, dz));
            nk[u] = pack_key(d2, jlow + 16 * u);
        }
        if (c < 7) {                        // prefetch next chunk during sort
            sp += 128;
#pragma unroll
            for (int u = 0; u < 8; ++u) buf[u] = sp[16 * u];
        }
        jlow += 128;

        sort8(nk);
        // keep-16-smallest: INF-padded bitonic half-merge, then clean
#pragma unroll
        for (int t = 0; t < 8; ++t)
            key[8 + t] = fmin(key[8 + t], nk[7 - t]);
        clean16(key);
    }

    // butterfly merge of the 16 slice lists; afterwards ALL 16 lanes of a
    // group hold the identical ascending top-16 of the query.
#pragma unroll
    for (int r = 1; r <= 8; r <<= 1) {
        double nk[16];
#pragma unroll
        for (int t = 0; t < 16; ++t)
            nk[t] = __shfl_xor(key[15 - t], r, 64);  // reversed partner list
#pragma unroll
        for (int t = 0; t < 16; ++t)
            key[t] = fmin(key[t], nk[t]);            // stride-16 half-cleaner
        clean16(key);
    }

    // ---- fused epilogue: 16 lanes emit the query's 16 output rows ----
    // lane s<8: float4 slot s of x_j ; lane s>=8: enc float4 slot s-8
    float4* orow = (float4*)out + (size_t)(base + qi) * (K_ * 16);

    if (s < 8) {
        const float4* x4 = (const float4*)x;
#pragma unroll
        for (int k = 0; k < 16; ++k) {
            const int jl = (int)(u32)__double_as_longlong(key[k]);
            const float4 xj = x4[(size_t)(base + jl) * 8 + s];   // coalesced
            nt_store4(xj, &orow[k * 16 + s]);
        }
    } else {
        const int c4 = s - 8;               // enc float4 column 0..7
        const float4* W4 = (const float4*)Wm;   // W[10][32]: row = 8 float4
        float4 wcol[10];
#pragma unroll
        for (int m = 0; m < 10; ++m) wcol[m] = W4[m * 8 + c4];
        const float4 bb = ((const float4*)bv)[c4];
#pragma unroll
        for (int k = 0; k < 16; ++k) {
            const int jl = (int)(u32)__double_as_longlong(key[k]);
            const float4 pj = spos[jl];                          // broadcast
            const float rx = pix - pj.x, ry = piy - pj.y, rz = piz - pj.z;
            const float dist = sqrtf(rx * rx + ry * ry + rz * rz + 1e-12f);
            const float f[10] = {pix, piy, piz, pj.x, pj.y, pj.z, rx, ry, rz, dist};
            float4 acc = bb;
#pragma unroll
            for (int m = 0; m < 10; ++m) {
                acc.x = fmaf(f[m], wcol[m].x, acc.x);
                acc.y = fmaf(f[m], wcol[m].y, acc.y);
                acc.z = fmaf(f[m], wcol[m].z, acc.z);
                acc.w = fmaf(f[m], wcol[m].w, acc.w);
            }
            acc.x = fmaxf(acc.x, 0.0f);
            acc.y = fmaxf(acc.y, 0.0f);
            acc.z = fmaxf(acc.z, 0.0f);
            acc.w = fmaxf(acc.w, 0.0f);
            nt_store4(acc, &orow[k * 16 + 8 + c4]);
        }
    }
}

extern "C" void kernel_launch(void* const* d_in, const int* in_sizes, int n_in,
                              void* d_out, int out_size, void* d_ws, size_t ws_size,
                              hipStream_t stream) {
    const float* x   = (const float*)d_in[0];
    const float* pos = (const float*)d_in[1];
    // d_in[2] = batch (unused: equal-size contiguous clouds)
    const float* Wm  = (const float*)d_in[3];
    const float* bv  = (const float*)d_in[4];
    float* out = (float*)d_out;

    knn_fused<<<B_ * 128, NTK, 0, stream>>>(pos, x, Wm, bv, out);
}

// Round 11
// 47.740 us; speedup vs baseline: 1.1300x; 1.1300x over previous
//
#include <hip/hip_runtime.h>

typedef unsigned long long u64;
typedef unsigned int u32;

#define B_  32
#define S_  1024
#define K_  16
#define NTK 256     // threads/block
#define QPB 32      // queries per block (NTK/8)

// key = double whose bit pattern is (d2_f32_bits << 32) | j.
// d2 >= 0 -> high word in [0, 0x7F7FFFFF] -> positive finite double,
// so IEEE fmin/fmax (v_min_f64/v_max_f64) order keys exactly as u64.
__device__ __forceinline__ double pack_key(float d2, int j) {
    return __longlong_as_double(((u64)__float_as_uint(d2) << 32) | (u32)j);
}

// ascending compare-exchange: 2 VALU instrs
__device__ __forceinline__ void ce(double& a, double& b) {
    const double lo = fmin(a, b);
    const double hi = fmax(a, b);
    a = lo; b = hi;
}

// Batcher odd-even mergesort of 8 keys, 19 CE, depth 6, ascending
__device__ __forceinline__ void sort8(double (&k)[8]) {
    ce(k[0], k[1]); ce(k[2], k[3]); ce(k[4], k[5]); ce(k[6], k[7]);
    ce(k[0], k[2]); ce(k[1], k[3]); ce(k[4], k[6]); ce(k[5], k[7]);
    ce(k[1], k[2]); ce(k[5], k[6]);
    ce(k[0], k[4]); ce(k[1], k[5]); ce(k[2], k[6]); ce(k[3], k[7]);
    ce(k[2], k[4]); ce(k[3], k[5]);
    ce(k[1], k[2]); ce(k[3], k[4]); ce(k[5], k[6]);
}

// clean a bitonic 16-sequence into ascending order (4 stages, 32 CE)
__device__ __forceinline__ void clean16(double (&k)[16]) {
#pragma unroll
    for (int str = 8; str > 0; str >>= 1) {
#pragma unroll
        for (int t = 0; t < 16; ++t) {
            const int p = t ^ str;
            if (p > t) ce(k[t], k[p]);
        }
    }
}

__global__ __launch_bounds__(NTK, 4)
void knn_fused(const float* __restrict__ pos, const float* __restrict__ x,
               const float* __restrict__ Wm, const float* __restrict__ bv,
               float* __restrict__ out) {
    __shared__ float4 spos[S_];             // 16 KB

    const int tid   = threadIdx.x;
    const int cloud = blockIdx.x >> 5;      // 32 blocks per cloud
    const int qbase = (blockIdx.x & 31) * QPB;
    const int base  = cloud * S_;

    for (int r = tid; r < S_; r += NTK) {
        const float* p = pos + (size_t)(base + r) * 3;
        spos[r] = make_float4(p[0], p[1], p[2], 0.0f);
    }
    __syncthreads();

    const int s  = tid & 7;                 // slice: j = s (mod 8)
    const int qi = qbase + (tid >> 3);      // query within cloud
    const float4 pi = spos[qi];
    const float pix = pi.x, piy = pi.y, piz = pi.z;

    double key[16];
#pragma unroll
    for (int t = 0; t < 16; ++t)
        key[t] = __longlong_as_double(0x7FEFFFFFFFFFFFFFULL);  // > any real key

    const float4* sp = &spos[s];            // lane slice pointer, stride 8
    float4 buf[8];                          // software-pipelined chunk loads
#pragma unroll
    for (int u = 0; u < 8; ++u) buf[u] = sp[8 * u];

    int jlow = s;                           // local j of buf[0]
    for (int c = 0; c < 16; ++c) {          // 16 chunks x 8 candidates = 128
        double nk[8];
#pragma unroll
        for (int u = 0; u < 8; ++u) {
            // bit-exact numpy chain: no fma, (dx2+dy2)+dz2
            const float dx = __fsub_rn(pix, buf[u].x);
            const float dy = __fsub_rn(piy, buf[u].y);
            const float dz = __fsub_rn(piz, buf[u].z);
            const float d2 = __fadd_rn(
                __fadd_rn(__fmul_rn(dx, dx), __fmul_rn(dy, dy)),
                __fmul_rn(dz, dz));
            nk[u] = pack_key(d2, jlow + 8 * u);
        }
        if (c < 15) {                       // prefetch next chunk during sort
            sp += 64;
#pragma unroll
            for (int u = 0; u < 8; ++u) buf[u] = sp[8 * u];
        }
        jlow += 64;

        sort8(nk);
        // keep-16-smallest: INF-padded bitonic half-merge, then clean
#pragma unroll
        for (int t = 0; t < 8; ++t)
            key[8 + t] = fmin(key[8 + t], nk[7 - t]);
        clean16(key);
    }

    // butterfly merge of the 8 slice lists; afterwards ALL 8 lanes of a
    // group hold the identical ascending top-16 of the query.
#pragma unroll
    for (int r = 1; r <= 4; r <<= 1) {
        double nk[16];
#pragma unroll
        for (int t = 0; t < 16; ++t)
            nk[t] = __shfl_xor(key[15 - t], r, 64);  // reversed partner list
#pragma unroll
        for (int t = 0; t < 16; ++t)
            key[t] = fmin(key[t], nk[t]);            // stride-16 half-cleaner
        clean16(key);
    }

    // ---- fused epilogue: depth-3 software-pipelined gather/emit ----
    const float4* x4 = (const float4*)x;
    const float4* W4 = (const float4*)Wm;   // W[10][32]: row = 8 float4
    float4 wcol[10];
#pragma unroll
    for (int m = 0; m < 10; ++m) wcol[m] = W4[m * 8 + s];
    const float4 bb = ((const float4*)bv)[s];

    int jls[16];                            // neighbor local indices (regs)
#pragma unroll
    for (int k = 0; k < 16; ++k)
        jls[k] = (int)(u32)__double_as_longlong(key[k]);

    float4* orow = (float4*)out + (size_t)(base + qi) * (K_ * 16);

    float4 xjb[3], pjb[3];                  // depth-3 prefetch buffers
#pragma unroll
    for (int k = 0; k < 3; ++k) {
        xjb[k] = x4[(size_t)(base + jls[k]) * 8 + s];   // L2 gather in flight
        pjb[k] = spos[jls[k]];                          // LDS read in flight
    }
#pragma unroll
    for (int k = 0; k < 16; ++k) {
        const float4 xj = xjb[k % 3];       // static index after unroll
        const float4 pj = pjb[k % 3];
        if (k + 3 < 16) {                   // refill slot 3 iterations ahead
            xjb[k % 3] = x4[(size_t)(base + jls[k + 3]) * 8 + s];
            pjb[k % 3] = spos[jls[k + 3]];
        }
        const float rx = pix - pj.x, ry = piy - pj.y, rz = piz - pj.z;
        const float dist = sqrtf(rx * rx + ry * ry + rz * rz + 1e-12f);
        const float f[10] = {pix, piy, piz, pj.x, pj.y, pj.z, rx, ry, rz, dist};
        float4 acc = bb;
#pragma unroll
        for (int m = 0; m < 10; ++m) {
            acc.x = fmaf(f[m], wcol[m].x, acc.x);
            acc.y = fmaf(f[m], wcol[m].y, acc.y);
            acc.z = fmaf(f[m], wcol[m].z, acc.z);
            acc.w = fmaf(f[m], wcol[m].w, acc.w);
        }
        acc.x = fmaxf(acc.x, 0.0f);
        acc.y = fmaxf(acc.y, 0.0f);
        acc.z = fmaxf(acc.z, 0.0f);
        acc.w = fmaxf(acc.w, 0.0f);
        orow[k * 16 + s]     = xj;
        orow[k * 16 + 8 + s] = acc;
    }
}

extern "C" void kernel_launch(void* const* d_in, const int* in_sizes, int n_in,
                              void* d_out, int out_size, void* d_ws, size_t ws_size,
                              hipStream_t stream) {
    const float* x   = (const float*)d_in[0];
    const float* pos = (const float*)d_in[1];
    // d_in[2] = batch (unused: equal-size contiguous clouds)
    const float* Wm  = (const float*)d_in[3];
    const float* bv  = (const float*)d_in[4];
    float* out = (float*)d_out;

    knn_fused<<<B_ * 32, NTK, 0, stream>>>(pos, x, Wm, bv, out);
}